// Round 8
// baseline (856.979 us; speedup 1.0000x reference)
//
#include <hip/hip_runtime.h>
#include <cmath>

constexpr int Bx = 4, Nx = 512, Dx = 512, Hx = 8, DHx = 64, Kx = 10, Mx = 2048, Lx = 4;
constexpr float EPSx = 1e-5f;
typedef unsigned short u16;
typedef __attribute__((ext_vector_type(8))) short short8;
typedef __attribute__((ext_vector_type(4))) float f32x4;

__device__ __forceinline__ u16 f2bf(float f) {
  unsigned u = __builtin_bit_cast(unsigned, f);
  return (u16)((u + 0x7fffu + ((u >> 16) & 1u)) >> 16);   // RNE
}
__device__ __forceinline__ float bf2f(u16 h) {
  unsigned u = ((unsigned)h) << 16;
  return __builtin_bit_cast(float, u);
}
__device__ __forceinline__ void gload16(const void* g, void* l) {
  __builtin_amdgcn_global_load_lds((const __attribute__((address_space(1))) void*)g,
                                   (__attribute__((address_space(3))) void*)l, 16, 0, 0);
}
__device__ __forceinline__ float wave_max(float v) {
  #pragma unroll
  for (int off = 1; off < 64; off <<= 1) v = fmaxf(v, __shfl_xor(v, off));
  return v;
}
__device__ __forceinline__ float wave_sum(float v) {
  #pragma unroll
  for (int off = 1; off < 64; off <<= 1) v += __shfl_xor(v, off);
  return v;
}

// ---------------------------------------------------------------------------
// idx8[b,n,m] = clip(floor(||coord[b,n]-coord[b,m]||), 0, K-1)  (u8)
// ---------------------------------------------------------------------------
__global__ __launch_bounds__(256) void idx_kernel(const float* __restrict__ coord,
                                                  unsigned char* __restrict__ idx8) {
  int t = blockIdx.x * 256 + threadIdx.x;
  int m = t % Nx;
  int n = (t / Nx) % Nx;
  int b = t / (Nx * Nx);
  float dx = coord[(b * Nx + n) * 2 + 0] - coord[(b * Nx + m) * 2 + 0];
  float dy = coord[(b * Nx + n) * 2 + 1] - coord[(b * Nx + m) * 2 + 1];
  float dist = sqrtf(dx * dx + dy * dy);
  int bin = (int)floorf(dist);
  bin = bin < 0 ? 0 : (bin > Kx - 1 ? Kx - 1 : bin);
  idx8[t] = (unsigned char)bin;
}

// ---------------------------------------------------------------------------
// Weight transpose + bf16 hi/lo split:  W[K,N] fp32 -> T{hi,lo}[N,K] bf16.
// ---------------------------------------------------------------------------
__global__ __launch_bounds__(256) void wsplitT_kernel(const float* __restrict__ W,
                                                      u16* __restrict__ Thi,
                                                      u16* __restrict__ Tlo,
                                                      int K, int N, size_t dst_lstride) {
  __shared__ float tile[32][33];
  int l = blockIdx.z;
  const float* Wl = W + (size_t)l * K * N;
  u16* hi = Thi + (size_t)l * dst_lstride;
  u16* lo = Tlo + (size_t)l * dst_lstride;
  int n0 = blockIdx.x * 32, k0 = blockIdx.y * 32;
  int tx = threadIdx.x & 31, ty = threadIdx.x >> 5;
  #pragma unroll
  for (int i = 0; i < 4; i++) {
    int kk = ty + i * 8;
    tile[kk][tx] = Wl[(size_t)(k0 + kk) * N + n0 + tx];
  }
  __syncthreads();
  #pragma unroll
  for (int i = 0; i < 4; i++) {
    int nn = ty + i * 8;
    float v = tile[tx][nn];
    u16 h = f2bf(v);
    hi[(size_t)(n0 + nn) * K + k0 + tx] = h;
    lo[(size_t)(n0 + nn) * K + k0 + tx] = f2bf(v - bf2f(h));
  }
}

// ---------------------------------------------------------------------------
// Row LayerNorm (fp32 out) — final LN.
// ---------------------------------------------------------------------------
__global__ __launch_bounds__(256) void ln_kernel(const float* __restrict__ x,
                                                 const float* __restrict__ g,
                                                 const float* __restrict__ bta,
                                                 float* __restrict__ out) {
  __shared__ float red[256];
  int row = blockIdx.x;
  int tid = threadIdx.x;
  const float2 v = reinterpret_cast<const float2*>(x + (size_t)row * Dx)[tid];

  red[tid] = v.x + v.y;
  __syncthreads();
  for (int s = 128; s > 0; s >>= 1) { if (tid < s) red[tid] += red[tid + s]; __syncthreads(); }
  float mean = red[0] * (1.0f / Dx);
  __syncthreads();

  float d0 = v.x - mean, d1 = v.y - mean;
  red[tid] = d0 * d0 + d1 * d1;
  __syncthreads();
  for (int s = 128; s > 0; s >>= 1) { if (tid < s) red[tid] += red[tid + s]; __syncthreads(); }
  float rstd = rsqrtf(red[0] * (1.0f / Dx) + EPSx);
  __syncthreads();

  float2 gg = reinterpret_cast<const float2*>(g)[tid];
  float2 bb = reinterpret_cast<const float2*>(bta)[tid];
  float2 o;
  o.x = d0 * rstd * gg.x + bb.x;
  o.y = d1 * rstd * gg.y + bb.y;
  reinterpret_cast<float2*>(out + (size_t)row * Dx)[tid] = o;
}

// ---------------------------------------------------------------------------
// Row LayerNorm producing bf16 hi/lo split.
// ---------------------------------------------------------------------------
__global__ __launch_bounds__(256) void ln_split_kernel(const float* __restrict__ x,
                                                       const float* __restrict__ g,
                                                       const float* __restrict__ bta,
                                                       u16* __restrict__ hhi,
                                                       u16* __restrict__ hlo) {
  __shared__ float red[256];
  int row = blockIdx.x;
  int tid = threadIdx.x;
  const float2 v = reinterpret_cast<const float2*>(x + (size_t)row * Dx)[tid];

  red[tid] = v.x + v.y;
  __syncthreads();
  for (int s = 128; s > 0; s >>= 1) { if (tid < s) red[tid] += red[tid + s]; __syncthreads(); }
  float mean = red[0] * (1.0f / Dx);
  __syncthreads();

  float d0 = v.x - mean, d1 = v.y - mean;
  red[tid] = d0 * d0 + d1 * d1;
  __syncthreads();
  for (int s = 128; s > 0; s >>= 1) { if (tid < s) red[tid] += red[tid + s]; __syncthreads(); }
  float rstd = rsqrtf(red[0] * (1.0f / Dx) + EPSx);
  __syncthreads();

  float2 gg = reinterpret_cast<const float2*>(g)[tid];
  float2 bb = reinterpret_cast<const float2*>(bta)[tid];
  float ox = d0 * rstd * gg.x + bb.x;
  float oy = d1 * rstd * gg.y + bb.y;
  u16 hx = f2bf(ox), hy = f2bf(oy);
  ushort2 hv = {hx, hy};
  ushort2 lv = {f2bf(ox - bf2f(hx)), f2bf(oy - bf2f(hy))};
  reinterpret_cast<ushort2*>(hhi + (size_t)row * Dx)[tid] = hv;
  reinterpret_cast<ushort2*>(hlo + (size_t)row * Dx)[tid] = lv;
}

// ---------------------------------------------------------------------------
// Split-bf16 MFMA GEMM (non-split-K):  C = A @ B^T + bias.
// Used for w1 only (EPI=2: gelu -> split bf16 out).  BM=64, BN=128.
// ---------------------------------------------------------------------------
template <int BM, int BN, int EPI>
__global__ __launch_bounds__(256) void gemm_mfma(
    const u16* __restrict__ Ahi, const u16* __restrict__ Alo,
    const u16* __restrict__ Bhi, const u16* __restrict__ Blo,
    const float* __restrict__ bias,
    float* __restrict__ C, u16* __restrict__ Chi, u16* __restrict__ Clo,
    int M, int Nn, int Kk) {
  constexpr int FM = BM / 32, FN = BN / 32;
  __shared__ __align__(16) u16 lds[(BM + BN) * 64];
  u16* lAhi = lds;
  u16* lAlo = lds + BM * 32;
  u16* lBhi = lds + BM * 64;
  u16* lBlo = lds + BM * 64 + BN * 32;

  const int tid = threadIdx.x;
  const int lane = tid & 63;
  const int wid = tid >> 6;
  const int wr = wid >> 1, wc = wid & 1;
  const int row0 = blockIdx.y * BM, col0 = blockIdx.x * BN;
  const int kg = (lane >> 4) * 8;
  const int lr = lane & 15;

  f32x4 acc[FM][FN];
  #pragma unroll
  for (int m = 0; m < FM; m++)
    #pragma unroll
    for (int n = 0; n < FN; n++) acc[m][n] = (f32x4)(0.0f);

  constexpr int AR = (BM * 32) / 2048;
  constexpr int BR = (BN * 32) / 2048;

  for (int kt = 0; kt < Kk; kt += 32) {
    #pragma unroll
    for (int r = 0; r < AR; r++) {
      int e = r * 2048 + tid * 8;
      int row = e >> 5, kc = e & 31;
      size_t go = (size_t)(row0 + row) * Kk + kt + kc;
      gload16(Ahi + go, lAhi + e);
      gload16(Alo + go, lAlo + e);
    }
    #pragma unroll
    for (int r = 0; r < BR; r++) {
      int e = r * 2048 + tid * 8;
      int row = e >> 5, kc = e & 31;
      size_t go = (size_t)(col0 + row) * Kk + kt + kc;
      gload16(Bhi + go, lBhi + e);
      gload16(Blo + go, lBlo + e);
    }
    __syncthreads();

    short8 ah[FM], al[FM], bh[FN], bl[FN];
    #pragma unroll
    for (int m = 0; m < FM; m++) {
      int off = (wr * (BM / 2) + m * 16 + lr) * 32 + kg;
      ah[m] = *reinterpret_cast<const short8*>(lAhi + off);
      al[m] = *reinterpret_cast<const short8*>(lAlo + off);
    }
    #pragma unroll
    for (int n = 0; n < FN; n++) {
      int off = (wc * (BN / 2) + n * 16 + lr) * 32 + kg;
      bh[n] = *reinterpret_cast<const short8*>(lBhi + off);
      bl[n] = *reinterpret_cast<const short8*>(lBlo + off);
    }
    #pragma unroll
    for (int m = 0; m < FM; m++)
      #pragma unroll
      for (int n = 0; n < FN; n++) {
        acc[m][n] = __builtin_amdgcn_mfma_f32_16x16x32_bf16(ah[m], bh[n], acc[m][n], 0, 0, 0);
        acc[m][n] = __builtin_amdgcn_mfma_f32_16x16x32_bf16(ah[m], bl[n], acc[m][n], 0, 0, 0);
        acc[m][n] = __builtin_amdgcn_mfma_f32_16x16x32_bf16(al[m], bh[n], acc[m][n], 0, 0, 0);
      }
    __syncthreads();
  }

  const int rbase = (lane >> 4) * 4;
  #pragma unroll
  for (int m = 0; m < FM; m++) {
    #pragma unroll
    for (int n = 0; n < FN; n++) {
      int cidx = col0 + wc * (BN / 2) + n * 16 + lr;
      float bcol = bias[cidx];
      #pragma unroll
      for (int r = 0; r < 4; r++) {
        int row = row0 + wr * (BM / 2) + m * 16 + rbase + r;
        size_t o = (size_t)row * Nn + cidx;
        float val = acc[m][n][r] + bcol;
        if constexpr (EPI == 1) {
          C[o] = val + C[o];
        } else if constexpr (EPI == 2) {
          val = 0.5f * val * (1.0f + erff(val * 0.70710678118654752f));
          u16 h = f2bf(val);
          Chi[o] = h;
          Clo[o] = f2bf(val - bf2f(h));
        } else {
          u16 h = f2bf(val);
          Chi[o] = h;
          Clo[o] = f2bf(val - bf2f(h));
        }
      }
    }
  }
}

// ---------------------------------------------------------------------------
// Split-K GEMM with fp32 atomic accumulate:  C += A @ B^T (+bias from kz==0).
// C already holds the residual.  BM=64, BN=128, grid.z = Kk/KC slices.
// ---------------------------------------------------------------------------
template <int KC>
__global__ __launch_bounds__(256) void gemm_splitk(
    const u16* __restrict__ Ahi, const u16* __restrict__ Alo,
    const u16* __restrict__ Bhi, const u16* __restrict__ Blo,
    const float* __restrict__ bias, float* __restrict__ C,
    int M, int Nn, int Kk) {
  constexpr int BM = 64, BN = 128;
  constexpr int FM = 2, FN = 4;
  __shared__ __align__(16) u16 lds[(BM + BN) * 64];
  u16* lAhi = lds;
  u16* lAlo = lds + BM * 32;
  u16* lBhi = lds + BM * 64;
  u16* lBlo = lds + BM * 64 + BN * 32;

  const int tid = threadIdx.x;
  const int lane = tid & 63;
  const int wid = tid >> 6;
  const int wr = wid >> 1, wc = wid & 1;
  const int row0 = blockIdx.y * BM, col0 = blockIdx.x * BN;
  const int kz = blockIdx.z;
  const int kbase = kz * KC;
  const int kg = (lane >> 4) * 8;
  const int lr = lane & 15;

  f32x4 acc[FM][FN];
  #pragma unroll
  for (int m = 0; m < FM; m++)
    #pragma unroll
    for (int n = 0; n < FN; n++) acc[m][n] = (f32x4)(0.0f);

  for (int kt = kbase; kt < kbase + KC; kt += 32) {
    {
      int e = tid * 8;
      int row = e >> 5, kc = e & 31;
      size_t go = (size_t)(row0 + row) * Kk + kt + kc;
      gload16(Ahi + go, lAhi + e);
      gload16(Alo + go, lAlo + e);
    }
    #pragma unroll
    for (int r = 0; r < 2; r++) {
      int e = r * 2048 + tid * 8;
      int row = e >> 5, kc = e & 31;
      size_t go = (size_t)(col0 + row) * Kk + kt + kc;
      gload16(Bhi + go, lBhi + e);
      gload16(Blo + go, lBlo + e);
    }
    __syncthreads();

    short8 ah[FM], al[FM], bh[FN], bl[FN];
    #pragma unroll
    for (int m = 0; m < FM; m++) {
      int off = (wr * 32 + m * 16 + lr) * 32 + kg;
      ah[m] = *reinterpret_cast<const short8*>(lAhi + off);
      al[m] = *reinterpret_cast<const short8*>(lAlo + off);
    }
    #pragma unroll
    for (int n = 0; n < FN; n++) {
      int off = (wc * 64 + n * 16 + lr) * 32 + kg;
      bh[n] = *reinterpret_cast<const short8*>(lBhi + off);
      bl[n] = *reinterpret_cast<const short8*>(lBlo + off);
    }
    #pragma unroll
    for (int m = 0; m < FM; m++)
      #pragma unroll
      for (int n = 0; n < FN; n++) {
        acc[m][n] = __builtin_amdgcn_mfma_f32_16x16x32_bf16(ah[m], bh[n], acc[m][n], 0, 0, 0);
        acc[m][n] = __builtin_amdgcn_mfma_f32_16x16x32_bf16(ah[m], bl[n], acc[m][n], 0, 0, 0);
        acc[m][n] = __builtin_amdgcn_mfma_f32_16x16x32_bf16(al[m], bh[n], acc[m][n], 0, 0, 0);
      }
    __syncthreads();
  }

  const int rbase = (lane >> 4) * 4;
  #pragma unroll
  for (int m = 0; m < FM; m++) {
    #pragma unroll
    for (int n = 0; n < FN; n++) {
      int cidx = col0 + wc * 64 + n * 16 + lr;
      float bcol = (kz == 0) ? bias[cidx] : 0.0f;
      #pragma unroll
      for (int r = 0; r < 4; r++) {
        int row = row0 + wr * 32 + m * 16 + rbase + r;
        atomicAdd(&C[(size_t)row * Nn + cidx], acc[m][n][r] + bcol);
      }
    }
  }
}

// ---------------------------------------------------------------------------
// Fused QKV GEMM: [2048,512] @ wqkvT[1536,512]^T, BM=BN=64 (768 blocks).
// cols 0-511 -> Q split; 512-1023 -> K split; 1024-1535 -> V split TRANSPOSED.
// ---------------------------------------------------------------------------
__global__ __launch_bounds__(256) void gemm_qkv(
    const u16* __restrict__ Ahi, const u16* __restrict__ Alo,
    const u16* __restrict__ Bhi, const u16* __restrict__ Blo,
    const float* __restrict__ bq, const float* __restrict__ bk,
    const float* __restrict__ bv,
    u16* __restrict__ qhi, u16* __restrict__ qlo,
    u16* __restrict__ khi, u16* __restrict__ klo,
    u16* __restrict__ vThi, u16* __restrict__ vTlo) {
  constexpr int Kk = 512;
  __shared__ __align__(16) u16 lds[128 * 64];
  u16* lAhi = lds;
  u16* lAlo = lds + 2048;
  u16* lBhi = lds + 4096;
  u16* lBlo = lds + 6144;

  const int tid = threadIdx.x;
  const int lane = tid & 63;
  const int wid = tid >> 6;
  const int wr = wid >> 1, wc = wid & 1;
  const int row0 = blockIdx.y * 64, col0 = blockIdx.x * 64;
  const int kg = (lane >> 4) * 8;
  const int lr = lane & 15;

  f32x4 acc[2][2];
  #pragma unroll
  for (int m = 0; m < 2; m++)
    #pragma unroll
    for (int n = 0; n < 2; n++) acc[m][n] = (f32x4)(0.0f);

  for (int kt = 0; kt < Kk; kt += 32) {
    int e = tid * 8;
    int row = e >> 5, kc = e & 31;
    size_t ga = (size_t)(row0 + row) * Kk + kt + kc;
    size_t gb = (size_t)(col0 + row) * Kk + kt + kc;
    gload16(Ahi + ga, lAhi + e);
    gload16(Alo + ga, lAlo + e);
    gload16(Bhi + gb, lBhi + e);
    gload16(Blo + gb, lBlo + e);
    __syncthreads();

    short8 ah[2], al[2], bh[2], bl[2];
    #pragma unroll
    for (int m = 0; m < 2; m++) {
      int off = (wr * 32 + m * 16 + lr) * 32 + kg;
      ah[m] = *reinterpret_cast<const short8*>(lAhi + off);
      al[m] = *reinterpret_cast<const short8*>(lAlo + off);
    }
    #pragma unroll
    for (int n = 0; n < 2; n++) {
      int off = (wc * 32 + n * 16 + lr) * 32 + kg;
      bh[n] = *reinterpret_cast<const short8*>(lBhi + off);
      bl[n] = *reinterpret_cast<const short8*>(lBlo + off);
    }
    #pragma unroll
    for (int m = 0; m < 2; m++)
      #pragma unroll
      for (int n = 0; n < 2; n++) {
        acc[m][n] = __builtin_amdgcn_mfma_f32_16x16x32_bf16(ah[m], bh[n], acc[m][n], 0, 0, 0);
        acc[m][n] = __builtin_amdgcn_mfma_f32_16x16x32_bf16(ah[m], bl[n], acc[m][n], 0, 0, 0);
        acc[m][n] = __builtin_amdgcn_mfma_f32_16x16x32_bf16(al[m], bh[n], acc[m][n], 0, 0, 0);
      }
    __syncthreads();
  }

  const int rbase = (lane >> 4) * 4;
  #pragma unroll
  for (int m = 0; m < 2; m++) {
    #pragma unroll
    for (int n = 0; n < 2; n++) {
      int cidx = col0 + wc * 32 + n * 16 + lr;                // 0..1535
      float bcol = cidx < 512 ? bq[cidx]
                  : (cidx < 1024 ? bk[cidx - 512] : bv[cidx - 1024]);
      #pragma unroll
      for (int r = 0; r < 4; r++) {
        int row = row0 + wr * 32 + m * 16 + rbase + r;        // 0..2047
        float val = acc[m][n][r] + bcol;
        u16 h = f2bf(val);
        u16 lo2 = f2bf(val - bf2f(h));
        if (cidx < 512) {
          size_t o = (size_t)row * 512 + cidx;
          qhi[o] = h; qlo[o] = lo2;
        } else if (cidx < 1024) {
          size_t o = (size_t)row * 512 + (cidx - 512);
          khi[o] = h; klo[o] = lo2;
        } else {
          size_t o = (size_t)(cidx - 1024) * 2048 + row;      // V transposed
          vThi[o] = h; vTlo[o] = lo2;
        }
      }
    }
  }
}

// ---------------------------------------------------------------------------
// qrel[b,n,h,kbin] = q[b,n,h*DH:] . rel_k[kbin,:]   (q reconstructed hi+lo)
// ---------------------------------------------------------------------------
__global__ __launch_bounds__(256) void qrel_kernel(const u16* __restrict__ qhi,
                                                   const u16* __restrict__ qlo,
                                                   const float* __restrict__ relk,
                                                   float* __restrict__ qrel) {
  int t = blockIdx.x * 256 + threadIdx.x;
  if (t >= Bx * Nx * Hx * Kx) return;
  int kbin = t % Kx;
  int h = (t / Kx) % Hx;
  int bn = t / (Kx * Hx);
  size_t base = (size_t)bn * Dx + h * DHx;
  const float* rr = relk + kbin * DHx;
  float s = 0.f;
  #pragma unroll
  for (int d = 0; d < DHx; d++)
    s += (bf2f(qhi[base + d]) + bf2f(qlo[base + d])) * rr[d];
  qrel[t] = s;
}

// ---------------------------------------------------------------------------
// FUSED ATTENTION: per (bh, 32-row n-tile):
//   scores = (QK^T + qrel[idx]) * 0.125  -> LDS fp32 [32][512]
//   row softmax + 10-bin histogram       -> P bf16 LDS [32][520], bins LDS
//   O = P@V + bins@rel_v                 -> split-bf16 out
// grid (16, 32); 256 thr = 4 waves (2 n-halves x 2 m/dh-halves).
// ---------------------------------------------------------------------------
__global__ __launch_bounds__(256) void attn_fused(
    const u16* __restrict__ qhi, const u16* __restrict__ qlo,
    const u16* __restrict__ khi, const u16* __restrict__ klo,
    const u16* __restrict__ vThi, const u16* __restrict__ vTlo,
    const float* __restrict__ qrel, const unsigned char* __restrict__ idx8,
    const float* __restrict__ rel_v,
    u16* __restrict__ ohi, u16* __restrict__ olo) {
  __shared__ float sc[32][512];                 // 64 KB scores
  __shared__ u16 lP[32][520];                   // 33.3 KB P (padded: 2-way banks)
  __shared__ __align__(16) u16 stg[4][2048];    // 16 KB K/V stage: [hi c0, hi c1, lo c0, lo c1]
  __shared__ float binsS[32][Kx];
  __shared__ float RelVs[Kx][DHx];

  const int bh = blockIdx.y;
  const int b = bh >> 3, h = bh & 7;
  const int n0 = blockIdx.x * 32;
  const int tid = threadIdx.x;
  const int lane = tid & 63;
  const int wid = tid >> 6;
  const int wr = wid >> 1, wc = wid & 1;
  const int kg = (lane >> 4) * 8;
  const int lr = lane & 15;
  const int rbase = (lane >> 4) * 4;

  for (int t = tid; t < Kx * DHx; t += 256)
    RelVs[t / DHx][t % DHx] = rel_v[t];

  // Q fragments in registers (row n0+wr*16+lr, k-chunks 0/1)
  short8 qh[2], ql[2];
  {
    size_t qb = (size_t)(b * Nx + n0 + wr * 16 + lr) * Dx + h * DHx + kg;
    qh[0] = *reinterpret_cast<const short8*>(qhi + qb);
    qh[1] = *reinterpret_cast<const short8*>(qhi + qb + 32);
    ql[0] = *reinterpret_cast<const short8*>(qlo + qb);
    ql[1] = *reinterpret_cast<const short8*>(qlo + qb + 32);
  }

  // ---- phase 1: QK^T + bias -> sc ----
  for (int mt = 0; mt < Nx; mt += 64) {
    {
      int e = tid * 8;
      int row = e >> 5;
      size_t kb = (size_t)(b * Nx + mt + row) * Dx + h * DHx + (e & 31);
      gload16(khi + kb, &stg[0][e]);
      gload16(khi + kb + 32, &stg[1][e]);
      gload16(klo + kb, &stg[2][e]);
      gload16(klo + kb + 32, &stg[3][e]);
    }
    __syncthreads();

    f32x4 acc[2];
    acc[0] = (f32x4)(0.0f);
    acc[1] = (f32x4)(0.0f);
    #pragma unroll
    for (int f = 0; f < 2; f++) {
      int boff = (wc * 32 + f * 16 + lr) * 32 + kg;
      short8 kh0 = *reinterpret_cast<const short8*>(&stg[0][boff]);
      short8 kh1 = *reinterpret_cast<const short8*>(&stg[1][boff]);
      short8 kl0 = *reinterpret_cast<const short8*>(&stg[2][boff]);
      short8 kl1 = *reinterpret_cast<const short8*>(&stg[3][boff]);
      acc[f] = __builtin_amdgcn_mfma_f32_16x16x32_bf16(qh[0], kh0, acc[f], 0, 0, 0);
      acc[f] = __builtin_amdgcn_mfma_f32_16x16x32_bf16(qh[1], kh1, acc[f], 0, 0, 0);
      acc[f] = __builtin_amdgcn_mfma_f32_16x16x32_bf16(qh[0], kl0, acc[f], 0, 0, 0);
      acc[f] = __builtin_amdgcn_mfma_f32_16x16x32_bf16(qh[1], kl1, acc[f], 0, 0, 0);
      acc[f] = __builtin_amdgcn_mfma_f32_16x16x32_bf16(ql[0], kh0, acc[f], 0, 0, 0);
      acc[f] = __builtin_amdgcn_mfma_f32_16x16x32_bf16(ql[1], kh1, acc[f], 0, 0, 0);
    }
    #pragma unroll
    for (int f = 0; f < 2; f++) {
      int mloc = wc * 32 + f * 16 + lr;
      int mg = mt + mloc;
      #pragma unroll
      for (int r = 0; r < 4; r++) {
        int nl = wr * 16 + rbase + r;
        int ng = n0 + nl;
        unsigned char iv = idx8[(size_t)(b * Nx + ng) * Nx + mg];
        float bias = qrel[((size_t)(b * Nx + ng) * Hx + h) * Kx + iv];
        sc[nl][mg] = (acc[f][r] + bias) * 0.125f;
      }
    }
    __syncthreads();
  }

  // ---- phase 2: softmax + histogram -> lP, binsS ----
  for (int rr = 0; rr < 8; rr++) {
    int nl = wid * 8 + rr;
    int ng = n0 + nl;
    float4 v0 = *reinterpret_cast<const float4*>(&sc[nl][lane * 8]);
    float4 v1 = *reinterpret_cast<const float4*>(&sc[nl][lane * 8 + 4]);
    float p[8] = {v0.x, v0.y, v0.z, v0.w, v1.x, v1.y, v1.z, v1.w};

    float mx = p[0];
    #pragma unroll
    for (int j = 1; j < 8; j++) mx = fmaxf(mx, p[j]);
    mx = wave_max(mx);

    float sum = 0.f;
    #pragma unroll
    for (int j = 0; j < 8; j++) { p[j] = expf(p[j] - mx); sum += p[j]; }
    sum = wave_sum(sum);
    float inv = 1.0f / sum;

    const unsigned char* idr = idx8 + (size_t)(b * Nx + ng) * Nx + lane * 8;
    uchar4 c0 = *reinterpret_cast<const uchar4*>(idr);
    uchar4 c1 = *reinterpret_cast<const uchar4*>(idr + 4);
    int iv[8] = {c0.x, c0.y, c0.z, c0.w, c1.x, c1.y, c1.z, c1.w};

    float bins[Kx];
    #pragma unroll
    for (int kk = 0; kk < Kx; kk++) bins[kk] = 0.f;
    #pragma unroll
    for (int j = 0; j < 8; j++)
      #pragma unroll
      for (int kk = 0; kk < Kx; kk++) bins[kk] += (iv[j] == kk) ? p[j] : 0.f;
    #pragma unroll
    for (int kk = 0; kk < Kx; kk++) bins[kk] = wave_sum(bins[kk]);

    short8 sv;
    #pragma unroll
    for (int j = 0; j < 8; j++) sv[j] = (short)f2bf(p[j] * inv);
    *reinterpret_cast<short8*>(&lP[nl][lane * 8]) = sv;

    if (lane == 0) {
      #pragma unroll
      for (int kk = 0; kk < Kx; kk++) binsS[nl][kk] = bins[kk] * inv;
    }
  }
  __syncthreads();

  // ---- phase 3: O = P @ V ----
  f32x4 oacc[2];
  oacc[0] = (f32x4)(0.0f);
  oacc[1] = (f32x4)(0.0f);
  for (int mt = 0; mt < Nx; mt += 64) {
    {
      int e = tid * 8;
      int row = e >> 5;                         // dh 0..63
      size_t vb = (size_t)(h * DHx + row) * 2048 + b * Nx + mt + (e & 31);
      gload16(vThi + vb, &stg[0][e]);
      gload16(vThi + vb + 32, &stg[1][e]);
      gload16(vTlo + vb, &stg[2][e]);
      gload16(vTlo + vb + 32, &stg[3][e]);
    }
    __syncthreads();

    short8 pa0 = *reinterpret_cast<const short8*>(&lP[wr * 16 + lr][mt + kg]);
    short8 pa1 = *reinterpret_cast<const short8*>(&lP[wr * 16 + lr][mt + 32 + kg]);
    #pragma unroll
    for (int f = 0; f < 2; f++) {
      int boff = (wc * 32 + f * 16 + lr) * 32 + kg;
      short8 vh0 = *reinterpret_cast<const short8*>(&stg[0][boff]);
      short8 vh1 = *reinterpret_cast<const short8*>(&stg[1][boff]);
      short8 vl0 = *reinterpret_cast<const short8*>(&stg[2][boff]);
      short8 vl1 = *reinterpret_cast<const short8*>(&stg[3][boff]);
      oacc[f] = __builtin_amdgcn_mfma_f32_16x16x32_bf16(pa0, vh0, oacc[f], 0, 0, 0);
      oacc[f] = __builtin_amdgcn_mfma_f32_16x16x32_bf16(pa1, vh1, oacc[f], 0, 0, 0);
      oacc[f] = __builtin_amdgcn_mfma_f32_16x16x32_bf16(pa0, vl0, oacc[f], 0, 0, 0);
      oacc[f] = __builtin_amdgcn_mfma_f32_16x16x32_bf16(pa1, vl1, oacc[f], 0, 0, 0);
    }
    __syncthreads();
  }

  // ---- epilogue: + bins@rel_v, split-bf16 out ----
  #pragma unroll
  for (int f = 0; f < 2; f++) {
    int dl = wc * 32 + f * 16 + lr;
    float rv[Kx];
    #pragma unroll
    for (int kk = 0; kk < Kx; kk++) rv[kk] = RelVs[kk][dl];
    #pragma unroll
    for (int r = 0; r < 4; r++) {
      int nl = wr * 16 + rbase + r;
      float val = oacc[f][r];
      #pragma unroll
      for (int kk = 0; kk < Kx; kk++) val += binsS[nl][kk] * rv[kk];
      size_t oo = (size_t)(b * Nx + n0 + nl) * Dx + h * DHx + dl;
      u16 hh = f2bf(val);
      ohi[oo] = hh;
      olo[oo] = f2bf(val - bf2f(hh));
    }
  }
}

// ---------------------------------------------------------------------------
extern "C" void kernel_launch(void* const* d_in, const int* in_sizes, int n_in,
                              void* d_out, int out_size, void* d_ws, size_t ws_size,
                              hipStream_t stream) {
  const float* x_in  = (const float*)d_in[0];
  const float* coord = (const float*)d_in[1];
  const float* ln1_g = (const float*)d_in[2];
  const float* ln1_b = (const float*)d_in[3];
  const float* wq    = (const float*)d_in[4];
  const float* bq    = (const float*)d_in[5];
  const float* wk    = (const float*)d_in[6];
  const float* bk    = (const float*)d_in[7];
  const float* wv    = (const float*)d_in[8];
  const float* bv    = (const float*)d_in[9];
  const float* wo    = (const float*)d_in[10];
  const float* bo    = (const float*)d_in[11];
  const float* rel_k = (const float*)d_in[12];
  const float* rel_v = (const float*)d_in[13];
  const float* ln2_g = (const float*)d_in[14];
  const float* ln2_b = (const float*)d_in[15];
  const float* w1    = (const float*)d_in[16];
  const float* b1    = (const float*)d_in[17];
  const float* w2    = (const float*)d_in[18];
  const float* b2    = (const float*)d_in[19];
  const float* lnf_g = (const float*)d_in[20];
  const float* lnf_b = (const float*)d_in[21];

  float* x = (float*)d_out;
  constexpr size_t BND  = (size_t)Bx * Nx * Dx;       // 1048576
  constexpr size_t SC   = (size_t)Bx * Hx * Nx * Nx;  // 8388608
  constexpr size_t RELS = (size_t)Bx * Nx * Hx * Kx;
  constexpr size_t QKVW = (size_t)1536 * 512;

  char* w = (char*)d_ws;
  size_t off = 0;
  auto nxt = [&](size_t bytes) -> void* {
    void* p = w + off;
    off = (off + bytes + 255) & ~(size_t)255;
    return p;
  };
  unsigned char* idxb = (unsigned char*)nxt((size_t)Bx * Nx * Nx);
  float* scores = (float*)nxt(4ull * SC);             // now only used as ffn1-split alias
  float* qrel   = (float*)nxt(4ull * RELS);
  u16* qhi = (u16*)nxt(2ull * BND);
  u16* qlo = (u16*)nxt(2ull * BND);
  u16* khi = (u16*)nxt(2ull * BND);
  u16* klo = (u16*)nxt(2ull * BND);
  u16* vThi = (u16*)nxt(2ull * BND);
  u16* vTlo = (u16*)nxt(2ull * BND);
  u16* hhi = (u16*)nxt(2ull * BND);
  u16* hlo = (u16*)nxt(2ull * BND);
  u16* ohi = (u16*)nxt(2ull * BND);
  u16* olo = (u16*)nxt(2ull * BND);
  u16* wqkvThi = (u16*)nxt(2ull * Lx * QKVW);
  u16* wqkvTlo = (u16*)nxt(2ull * Lx * QKVW);
  u16* woThi = (u16*)nxt(2ull * Lx * Dx * Dx);
  u16* woTlo = (u16*)nxt(2ull * Lx * Dx * Dx);
  u16* w1Thi = (u16*)nxt(2ull * Lx * Dx * Mx);
  u16* w1Tlo = (u16*)nxt(2ull * Lx * Dx * Mx);
  u16* w2Thi = (u16*)nxt(2ull * Lx * Mx * Dx);
  u16* w2Tlo = (u16*)nxt(2ull * Lx * Mx * Dx);
  u16* f1hi = (u16*)scores;
  u16* f1lo = f1hi + (size_t)(Bx * Nx) * Mx;

  hipMemcpyAsync(x, x_in, BND * sizeof(float), hipMemcpyDeviceToDevice, stream);
  idx_kernel<<<(Bx * Nx * Nx) / 256, 256, 0, stream>>>(coord, idxb);

  dim3 gw(Dx / 32, Dx / 32, Lx);
  wsplitT_kernel<<<gw, 256, 0, stream>>>(wq, wqkvThi, wqkvTlo, Dx, Dx, QKVW);
  wsplitT_kernel<<<gw, 256, 0, stream>>>(wk, wqkvThi + (size_t)512 * 512,
                                         wqkvTlo + (size_t)512 * 512, Dx, Dx, QKVW);
  wsplitT_kernel<<<gw, 256, 0, stream>>>(wv, wqkvThi + (size_t)1024 * 512,
                                         wqkvTlo + (size_t)1024 * 512, Dx, Dx, QKVW);
  wsplitT_kernel<<<gw, 256, 0, stream>>>(wo, woThi, woTlo, Dx, Dx, (size_t)Dx * Dx);
  wsplitT_kernel<<<dim3(Mx / 32, Dx / 32, Lx), 256, 0, stream>>>(
      w1, w1Thi, w1Tlo, Dx, Mx, (size_t)Dx * Mx);
  wsplitT_kernel<<<dim3(Dx / 32, Mx / 32, Lx), 256, 0, stream>>>(
      w2, w2Thi, w2Tlo, Mx, Dx, (size_t)Mx * Dx);

  const int Mrows = Bx * Nx;                 // 2048
  dim3 gqkv(1536 / 64, Mrows / 64);          // 768 blocks
  dim3 gw1(Mx / 128, Mrows / 64);            // 512 blocks
  dim3 gwo(Dx / 128, Mrows / 64, 4);         // 512 blocks, KC=128
  dim3 gw2(Dx / 128, Mrows / 64, 4);         // 512 blocks, KC=512
  dim3 gat(Nx / 32, Bx * Hx);                // (16,32) = 512 blocks

  for (int l = 0; l < Lx; l++) {
    size_t wD = (size_t)l * Dx * Dx;
    size_t w1o = (size_t)l * Dx * Mx;
    size_t w2o = (size_t)l * Mx * Dx;

    ln_split_kernel<<<Mrows, 256, 0, stream>>>(x, ln1_g + l * Dx, ln1_b + l * Dx, hhi, hlo);
    gemm_qkv<<<gqkv, 256, 0, stream>>>(hhi, hlo,
                                       wqkvThi + (size_t)l * QKVW, wqkvTlo + (size_t)l * QKVW,
                                       bq + l * Dx, bk + l * Dx, bv + l * Dx,
                                       qhi, qlo, khi, klo, vThi, vTlo);
    qrel_kernel<<<(Bx * Nx * Hx * Kx + 255) / 256, 256, 0, stream>>>(
        qhi, qlo, rel_k + (size_t)l * Kx * DHx, qrel);
    attn_fused<<<gat, 256, 0, stream>>>(qhi, qlo, khi, klo, vThi, vTlo,
                                        qrel, idxb, rel_v + (size_t)l * Kx * DHx,
                                        ohi, olo);
    gemm_splitk<128><<<gwo, 256, 0, stream>>>(ohi, olo, woThi + wD, woTlo + wD,
                                              bo + l * Dx, x, Mrows, Dx, Dx);
    ln_split_kernel<<<Mrows, 256, 0, stream>>>(x, ln2_g + l * Dx, ln2_b + l * Dx, hhi, hlo);
    gemm_mfma<64, 128, 2><<<gw1, 256, 0, stream>>>(hhi, hlo, w1Thi + w1o, w1Tlo + w1o,
                                                   b1 + l * Mx, nullptr, f1hi, f1lo,
                                                   Mrows, Mx, Dx);
    gemm_splitk<512><<<gw2, 256, 0, stream>>>(f1hi, f1lo, w2Thi + w2o, w2Tlo + w2o,
                                              b2 + l * Dx, x, Mrows, Dx, Mx);
  }
  ln_kernel<<<Mrows, 256, 0, stream>>>(x, lnf_g, lnf_b, x);
}

// Round 9
// 789.714 us; speedup vs baseline: 1.0852x; 1.0852x over previous
//
#include <hip/hip_runtime.h>
#include <cmath>

constexpr int Bx = 4, Nx = 512, Dx = 512, Hx = 8, DHx = 64, Kx = 10, Mx = 2048, Lx = 4;
constexpr float EPSx = 1e-5f;
typedef unsigned short u16;
typedef __attribute__((ext_vector_type(8))) short short8;
typedef __attribute__((ext_vector_type(4))) float f32x4;

__device__ __forceinline__ u16 f2bf(float f) {
  unsigned u = __builtin_bit_cast(unsigned, f);
  return (u16)((u + 0x7fffu + ((u >> 16) & 1u)) >> 16);   // RNE
}
__device__ __forceinline__ float bf2f(u16 h) {
  unsigned u = ((unsigned)h) << 16;
  return __builtin_bit_cast(float, u);
}
__device__ __forceinline__ void gload16(const void* g, void* l) {
  __builtin_amdgcn_global_load_lds((const __attribute__((address_space(1))) void*)g,
                                   (__attribute__((address_space(3))) void*)l, 16, 0, 0);
}
__device__ __forceinline__ float wave_max(float v) {
  #pragma unroll
  for (int off = 1; off < 64; off <<= 1) v = fmaxf(v, __shfl_xor(v, off));
  return v;
}
__device__ __forceinline__ float wave_sum(float v) {
  #pragma unroll
  for (int off = 1; off < 64; off <<= 1) v += __shfl_xor(v, off);
  return v;
}

// ---------------------------------------------------------------------------
// idx8[b,n,m] = clip(floor(||coord[b,n]-coord[b,m]||), 0, K-1)  (u8)
// ---------------------------------------------------------------------------
__global__ __launch_bounds__(256) void idx_kernel(const float* __restrict__ coord,
                                                  unsigned char* __restrict__ idx8) {
  int t = blockIdx.x * 256 + threadIdx.x;
  int m = t % Nx;
  int n = (t / Nx) % Nx;
  int b = t / (Nx * Nx);
  float dx = coord[(b * Nx + n) * 2 + 0] - coord[(b * Nx + m) * 2 + 0];
  float dy = coord[(b * Nx + n) * 2 + 1] - coord[(b * Nx + m) * 2 + 1];
  float dist = sqrtf(dx * dx + dy * dy);
  int bin = (int)floorf(dist);
  bin = bin < 0 ? 0 : (bin > Kx - 1 ? Kx - 1 : bin);
  idx8[t] = (unsigned char)bin;
}

// ---------------------------------------------------------------------------
// Weight transpose + bf16 hi/lo split:  W[K,N] fp32 -> T{hi,lo}[N,K] bf16.
// ---------------------------------------------------------------------------
__global__ __launch_bounds__(256) void wsplitT_kernel(const float* __restrict__ W,
                                                      u16* __restrict__ Thi,
                                                      u16* __restrict__ Tlo,
                                                      int K, int N, size_t dst_lstride) {
  __shared__ float tile[32][33];
  int l = blockIdx.z;
  const float* Wl = W + (size_t)l * K * N;
  u16* hi = Thi + (size_t)l * dst_lstride;
  u16* lo = Tlo + (size_t)l * dst_lstride;
  int n0 = blockIdx.x * 32, k0 = blockIdx.y * 32;
  int tx = threadIdx.x & 31, ty = threadIdx.x >> 5;
  #pragma unroll
  for (int i = 0; i < 4; i++) {
    int kk = ty + i * 8;
    tile[kk][tx] = Wl[(size_t)(k0 + kk) * N + n0 + tx];
  }
  __syncthreads();
  #pragma unroll
  for (int i = 0; i < 4; i++) {
    int nn = ty + i * 8;
    float v = tile[tx][nn];
    u16 h = f2bf(v);
    hi[(size_t)(n0 + nn) * K + k0 + tx] = h;
    lo[(size_t)(n0 + nn) * K + k0 + tx] = f2bf(v - bf2f(h));
  }
}

// ---------------------------------------------------------------------------
// Row LayerNorm (fp32 out) — final LN.
// ---------------------------------------------------------------------------
__global__ __launch_bounds__(256) void ln_kernel(const float* __restrict__ x,
                                                 const float* __restrict__ g,
                                                 const float* __restrict__ bta,
                                                 float* __restrict__ out) {
  __shared__ float red[256];
  int row = blockIdx.x;
  int tid = threadIdx.x;
  const float2 v = reinterpret_cast<const float2*>(x + (size_t)row * Dx)[tid];

  red[tid] = v.x + v.y;
  __syncthreads();
  for (int s = 128; s > 0; s >>= 1) { if (tid < s) red[tid] += red[tid + s]; __syncthreads(); }
  float mean = red[0] * (1.0f / Dx);
  __syncthreads();

  float d0 = v.x - mean, d1 = v.y - mean;
  red[tid] = d0 * d0 + d1 * d1;
  __syncthreads();
  for (int s = 128; s > 0; s >>= 1) { if (tid < s) red[tid] += red[tid + s]; __syncthreads(); }
  float rstd = rsqrtf(red[0] * (1.0f / Dx) + EPSx);
  __syncthreads();

  float2 gg = reinterpret_cast<const float2*>(g)[tid];
  float2 bb = reinterpret_cast<const float2*>(bta)[tid];
  float2 o;
  o.x = d0 * rstd * gg.x + bb.x;
  o.y = d1 * rstd * gg.y + bb.y;
  reinterpret_cast<float2*>(out + (size_t)row * Dx)[tid] = o;
}

// ---------------------------------------------------------------------------
// Row LayerNorm producing bf16 hi/lo split.
// ---------------------------------------------------------------------------
__global__ __launch_bounds__(256) void ln_split_kernel(const float* __restrict__ x,
                                                       const float* __restrict__ g,
                                                       const float* __restrict__ bta,
                                                       u16* __restrict__ hhi,
                                                       u16* __restrict__ hlo) {
  __shared__ float red[256];
  int row = blockIdx.x;
  int tid = threadIdx.x;
  const float2 v = reinterpret_cast<const float2*>(x + (size_t)row * Dx)[tid];

  red[tid] = v.x + v.y;
  __syncthreads();
  for (int s = 128; s > 0; s >>= 1) { if (tid < s) red[tid] += red[tid + s]; __syncthreads(); }
  float mean = red[0] * (1.0f / Dx);
  __syncthreads();

  float d0 = v.x - mean, d1 = v.y - mean;
  red[tid] = d0 * d0 + d1 * d1;
  __syncthreads();
  for (int s = 128; s > 0; s >>= 1) { if (tid < s) red[tid] += red[tid + s]; __syncthreads(); }
  float rstd = rsqrtf(red[0] * (1.0f / Dx) + EPSx);
  __syncthreads();

  float2 gg = reinterpret_cast<const float2*>(g)[tid];
  float2 bb = reinterpret_cast<const float2*>(bta)[tid];
  float ox = d0 * rstd * gg.x + bb.x;
  float oy = d1 * rstd * gg.y + bb.y;
  u16 hx = f2bf(ox), hy = f2bf(oy);
  ushort2 hv = {hx, hy};
  ushort2 lv = {f2bf(ox - bf2f(hx)), f2bf(oy - bf2f(hy))};
  reinterpret_cast<ushort2*>(hhi + (size_t)row * Dx)[tid] = hv;
  reinterpret_cast<ushort2*>(hlo + (size_t)row * Dx)[tid] = lv;
}

// ---------------------------------------------------------------------------
// Split-bf16 MFMA GEMM (non-split-K):  C = A @ B^T + bias.
// Used for w1 only (EPI=2: gelu -> split bf16 out).  BM=64, BN=128.
// ---------------------------------------------------------------------------
template <int BM, int BN, int EPI>
__global__ __launch_bounds__(256) void gemm_mfma(
    const u16* __restrict__ Ahi, const u16* __restrict__ Alo,
    const u16* __restrict__ Bhi, const u16* __restrict__ Blo,
    const float* __restrict__ bias,
    float* __restrict__ C, u16* __restrict__ Chi, u16* __restrict__ Clo,
    int M, int Nn, int Kk) {
  constexpr int FM = BM / 32, FN = BN / 32;
  __shared__ __align__(16) u16 lds[(BM + BN) * 64];
  u16* lAhi = lds;
  u16* lAlo = lds + BM * 32;
  u16* lBhi = lds + BM * 64;
  u16* lBlo = lds + BM * 64 + BN * 32;

  const int tid = threadIdx.x;
  const int lane = tid & 63;
  const int wid = tid >> 6;
  const int wr = wid >> 1, wc = wid & 1;
  const int row0 = blockIdx.y * BM, col0 = blockIdx.x * BN;
  const int kg = (lane >> 4) * 8;
  const int lr = lane & 15;

  f32x4 acc[FM][FN];
  #pragma unroll
  for (int m = 0; m < FM; m++)
    #pragma unroll
    for (int n = 0; n < FN; n++) acc[m][n] = (f32x4)(0.0f);

  constexpr int AR = (BM * 32) / 2048;
  constexpr int BR = (BN * 32) / 2048;

  for (int kt = 0; kt < Kk; kt += 32) {
    #pragma unroll
    for (int r = 0; r < AR; r++) {
      int e = r * 2048 + tid * 8;
      int row = e >> 5, kc = e & 31;
      size_t go = (size_t)(row0 + row) * Kk + kt + kc;
      gload16(Ahi + go, lAhi + e);
      gload16(Alo + go, lAlo + e);
    }
    #pragma unroll
    for (int r = 0; r < BR; r++) {
      int e = r * 2048 + tid * 8;
      int row = e >> 5, kc = e & 31;
      size_t go = (size_t)(col0 + row) * Kk + kt + kc;
      gload16(Bhi + go, lBhi + e);
      gload16(Blo + go, lBlo + e);
    }
    __syncthreads();

    short8 ah[FM], al[FM], bh[FN], bl[FN];
    #pragma unroll
    for (int m = 0; m < FM; m++) {
      int off = (wr * (BM / 2) + m * 16 + lr) * 32 + kg;
      ah[m] = *reinterpret_cast<const short8*>(lAhi + off);
      al[m] = *reinterpret_cast<const short8*>(lAlo + off);
    }
    #pragma unroll
    for (int n = 0; n < FN; n++) {
      int off = (wc * (BN / 2) + n * 16 + lr) * 32 + kg;
      bh[n] = *reinterpret_cast<const short8*>(lBhi + off);
      bl[n] = *reinterpret_cast<const short8*>(lBlo + off);
    }
    #pragma unroll
    for (int m = 0; m < FM; m++)
      #pragma unroll
      for (int n = 0; n < FN; n++) {
        acc[m][n] = __builtin_amdgcn_mfma_f32_16x16x32_bf16(ah[m], bh[n], acc[m][n], 0, 0, 0);
        acc[m][n] = __builtin_amdgcn_mfma_f32_16x16x32_bf16(ah[m], bl[n], acc[m][n], 0, 0, 0);
        acc[m][n] = __builtin_amdgcn_mfma_f32_16x16x32_bf16(al[m], bh[n], acc[m][n], 0, 0, 0);
      }
    __syncthreads();
  }

  const int rbase = (lane >> 4) * 4;
  #pragma unroll
  for (int m = 0; m < FM; m++) {
    #pragma unroll
    for (int n = 0; n < FN; n++) {
      int cidx = col0 + wc * (BN / 2) + n * 16 + lr;
      float bcol = bias[cidx];
      #pragma unroll
      for (int r = 0; r < 4; r++) {
        int row = row0 + wr * (BM / 2) + m * 16 + rbase + r;
        size_t o = (size_t)row * Nn + cidx;
        float val = acc[m][n][r] + bcol;
        if constexpr (EPI == 1) {
          C[o] = val + C[o];
        } else if constexpr (EPI == 2) {
          val = 0.5f * val * (1.0f + erff(val * 0.70710678118654752f));
          u16 h = f2bf(val);
          Chi[o] = h;
          Clo[o] = f2bf(val - bf2f(h));
        } else {
          u16 h = f2bf(val);
          Chi[o] = h;
          Clo[o] = f2bf(val - bf2f(h));
        }
      }
    }
  }
}

// ---------------------------------------------------------------------------
// Split-K GEMM with fp32 atomic accumulate:  C += A @ B^T (+bias from kz==0).
// C already holds the residual.  BM=64, BN=128, grid.z = Kk/KC slices.
// ---------------------------------------------------------------------------
template <int KC>
__global__ __launch_bounds__(256) void gemm_splitk(
    const u16* __restrict__ Ahi, const u16* __restrict__ Alo,
    const u16* __restrict__ Bhi, const u16* __restrict__ Blo,
    const float* __restrict__ bias, float* __restrict__ C,
    int M, int Nn, int Kk) {
  constexpr int BM = 64, BN = 128;
  constexpr int FM = 2, FN = 4;
  __shared__ __align__(16) u16 lds[(BM + BN) * 64];
  u16* lAhi = lds;
  u16* lAlo = lds + BM * 32;
  u16* lBhi = lds + BM * 64;
  u16* lBlo = lds + BM * 64 + BN * 32;

  const int tid = threadIdx.x;
  const int lane = tid & 63;
  const int wid = tid >> 6;
  const int wr = wid >> 1, wc = wid & 1;
  const int row0 = blockIdx.y * BM, col0 = blockIdx.x * BN;
  const int kz = blockIdx.z;
  const int kbase = kz * KC;
  const int kg = (lane >> 4) * 8;
  const int lr = lane & 15;

  f32x4 acc[FM][FN];
  #pragma unroll
  for (int m = 0; m < FM; m++)
    #pragma unroll
    for (int n = 0; n < FN; n++) acc[m][n] = (f32x4)(0.0f);

  for (int kt = kbase; kt < kbase + KC; kt += 32) {
    {
      int e = tid * 8;
      int row = e >> 5, kc = e & 31;
      size_t go = (size_t)(row0 + row) * Kk + kt + kc;
      gload16(Ahi + go, lAhi + e);
      gload16(Alo + go, lAlo + e);
    }
    #pragma unroll
    for (int r = 0; r < 2; r++) {
      int e = r * 2048 + tid * 8;
      int row = e >> 5, kc = e & 31;
      size_t go = (size_t)(col0 + row) * Kk + kt + kc;
      gload16(Bhi + go, lBhi + e);
      gload16(Blo + go, lBlo + e);
    }
    __syncthreads();

    short8 ah[FM], al[FM], bh[FN], bl[FN];
    #pragma unroll
    for (int m = 0; m < FM; m++) {
      int off = (wr * 32 + m * 16 + lr) * 32 + kg;
      ah[m] = *reinterpret_cast<const short8*>(lAhi + off);
      al[m] = *reinterpret_cast<const short8*>(lAlo + off);
    }
    #pragma unroll
    for (int n = 0; n < FN; n++) {
      int off = (wc * 64 + n * 16 + lr) * 32 + kg;
      bh[n] = *reinterpret_cast<const short8*>(lBhi + off);
      bl[n] = *reinterpret_cast<const short8*>(lBlo + off);
    }
    #pragma unroll
    for (int m = 0; m < FM; m++)
      #pragma unroll
      for (int n = 0; n < FN; n++) {
        acc[m][n] = __builtin_amdgcn_mfma_f32_16x16x32_bf16(ah[m], bh[n], acc[m][n], 0, 0, 0);
        acc[m][n] = __builtin_amdgcn_mfma_f32_16x16x32_bf16(ah[m], bl[n], acc[m][n], 0, 0, 0);
        acc[m][n] = __builtin_amdgcn_mfma_f32_16x16x32_bf16(al[m], bh[n], acc[m][n], 0, 0, 0);
      }
    __syncthreads();
  }

  const int rbase = (lane >> 4) * 4;
  #pragma unroll
  for (int m = 0; m < FM; m++) {
    #pragma unroll
    for (int n = 0; n < FN; n++) {
      int cidx = col0 + wc * 64 + n * 16 + lr;
      float bcol = (kz == 0) ? bias[cidx] : 0.0f;
      #pragma unroll
      for (int r = 0; r < 4; r++) {
        int row = row0 + wr * 32 + m * 16 + rbase + r;
        atomicAdd(&C[(size_t)row * Nn + cidx], acc[m][n][r] + bcol);
      }
    }
  }
}

// ---------------------------------------------------------------------------
// Fused QKV GEMM: [2048,512] @ wqkvT[1536,512]^T, BM=BN=64 (768 blocks).
// cols 0-511 -> Q split; 512-1023 -> K split; 1024-1535 -> V split TRANSPOSED.
// ---------------------------------------------------------------------------
__global__ __launch_bounds__(256) void gemm_qkv(
    const u16* __restrict__ Ahi, const u16* __restrict__ Alo,
    const u16* __restrict__ Bhi, const u16* __restrict__ Blo,
    const float* __restrict__ bq, const float* __restrict__ bk,
    const float* __restrict__ bv,
    u16* __restrict__ qhi, u16* __restrict__ qlo,
    u16* __restrict__ khi, u16* __restrict__ klo,
    u16* __restrict__ vThi, u16* __restrict__ vTlo) {
  constexpr int Kk = 512;
  __shared__ __align__(16) u16 lds[128 * 64];
  u16* lAhi = lds;
  u16* lAlo = lds + 2048;
  u16* lBhi = lds + 4096;
  u16* lBlo = lds + 6144;

  const int tid = threadIdx.x;
  const int lane = tid & 63;
  const int wid = tid >> 6;
  const int wr = wid >> 1, wc = wid & 1;
  const int row0 = blockIdx.y * 64, col0 = blockIdx.x * 64;
  const int kg = (lane >> 4) * 8;
  const int lr = lane & 15;

  f32x4 acc[2][2];
  #pragma unroll
  for (int m = 0; m < 2; m++)
    #pragma unroll
    for (int n = 0; n < 2; n++) acc[m][n] = (f32x4)(0.0f);

  for (int kt = 0; kt < Kk; kt += 32) {
    int e = tid * 8;
    int row = e >> 5, kc = e & 31;
    size_t ga = (size_t)(row0 + row) * Kk + kt + kc;
    size_t gb = (size_t)(col0 + row) * Kk + kt + kc;
    gload16(Ahi + ga, lAhi + e);
    gload16(Alo + ga, lAlo + e);
    gload16(Bhi + gb, lBhi + e);
    gload16(Blo + gb, lBlo + e);
    __syncthreads();

    short8 ah[2], al[2], bh[2], bl[2];
    #pragma unroll
    for (int m = 0; m < 2; m++) {
      int off = (wr * 32 + m * 16 + lr) * 32 + kg;
      ah[m] = *reinterpret_cast<const short8*>(lAhi + off);
      al[m] = *reinterpret_cast<const short8*>(lAlo + off);
    }
    #pragma unroll
    for (int n = 0; n < 2; n++) {
      int off = (wc * 32 + n * 16 + lr) * 32 + kg;
      bh[n] = *reinterpret_cast<const short8*>(lBhi + off);
      bl[n] = *reinterpret_cast<const short8*>(lBlo + off);
    }
    #pragma unroll
    for (int m = 0; m < 2; m++)
      #pragma unroll
      for (int n = 0; n < 2; n++) {
        acc[m][n] = __builtin_amdgcn_mfma_f32_16x16x32_bf16(ah[m], bh[n], acc[m][n], 0, 0, 0);
        acc[m][n] = __builtin_amdgcn_mfma_f32_16x16x32_bf16(ah[m], bl[n], acc[m][n], 0, 0, 0);
        acc[m][n] = __builtin_amdgcn_mfma_f32_16x16x32_bf16(al[m], bh[n], acc[m][n], 0, 0, 0);
      }
    __syncthreads();
  }

  const int rbase = (lane >> 4) * 4;
  #pragma unroll
  for (int m = 0; m < 2; m++) {
    #pragma unroll
    for (int n = 0; n < 2; n++) {
      int cidx = col0 + wc * 32 + n * 16 + lr;                // 0..1535
      float bcol = cidx < 512 ? bq[cidx]
                  : (cidx < 1024 ? bk[cidx - 512] : bv[cidx - 1024]);
      #pragma unroll
      for (int r = 0; r < 4; r++) {
        int row = row0 + wr * 32 + m * 16 + rbase + r;        // 0..2047
        float val = acc[m][n][r] + bcol;
        u16 h = f2bf(val);
        u16 lo2 = f2bf(val - bf2f(h));
        if (cidx < 512) {
          size_t o = (size_t)row * 512 + cidx;
          qhi[o] = h; qlo[o] = lo2;
        } else if (cidx < 1024) {
          size_t o = (size_t)row * 512 + (cidx - 512);
          khi[o] = h; klo[o] = lo2;
        } else {
          size_t o = (size_t)(cidx - 1024) * 2048 + row;      // V transposed
          vThi[o] = h; vTlo[o] = lo2;
        }
      }
    }
  }
}

// ---------------------------------------------------------------------------
// qrel[b,n,h,kbin] = q[b,n,h*DH:] . rel_k[kbin,:]   (q reconstructed hi+lo)
// ---------------------------------------------------------------------------
__global__ __launch_bounds__(256) void qrel_kernel(const u16* __restrict__ qhi,
                                                   const u16* __restrict__ qlo,
                                                   const float* __restrict__ relk,
                                                   float* __restrict__ qrel) {
  int t = blockIdx.x * 256 + threadIdx.x;
  if (t >= Bx * Nx * Hx * Kx) return;
  int kbin = t % Kx;
  int h = (t / Kx) % Hx;
  int bn = t / (Kx * Hx);
  size_t base = (size_t)bn * Dx + h * DHx;
  const float* rr = relk + kbin * DHx;
  float s = 0.f;
  #pragma unroll
  for (int d = 0; d < DHx; d++)
    s += (bf2f(qhi[base + d]) + bf2f(qlo[base + d])) * rr[d];
  qrel[t] = s;
}

// ---------------------------------------------------------------------------
// scores[bh,n,m] = (q.k + qrel[b,n,h,idx[b,n,m]]) * 0.125  via split-bf16 MFMA
// ---------------------------------------------------------------------------
__global__ __launch_bounds__(256) void scores_mfma(
    const u16* __restrict__ qhi, const u16* __restrict__ qlo,
    const u16* __restrict__ khi, const u16* __restrict__ klo,
    const float* __restrict__ qrel, const unsigned char* __restrict__ idx8,
    float* __restrict__ scores) {
  __shared__ __align__(16) u16 lds[4 * 2048];
  u16* lQh = lds;
  u16* lQl = lds + 2048;
  u16* lKh = lds + 4096;
  u16* lKl = lds + 6144;

  const int bh = blockIdx.z;
  const int b = bh >> 3, h = bh & 7;
  const int n0 = blockIdx.y * 64, m0 = blockIdx.x * 64;
  const int tid = threadIdx.x;
  const int lane = tid & 63;
  const int wid = tid >> 6;
  const int wr = wid >> 1, wc = wid & 1;
  const int kg = (lane >> 4) * 8;
  const int lr = lane & 15;

  f32x4 acc[2][2];
  #pragma unroll
  for (int m = 0; m < 2; m++)
    #pragma unroll
    for (int n = 0; n < 2; n++) acc[m][n] = (f32x4)(0.0f);

  for (int kt = 0; kt < DHx; kt += 32) {
    int e = tid * 8;
    int row = e >> 5, kc = e & 31;
    size_t gq = (size_t)(b * Nx + n0 + row) * Dx + h * DHx + kt + kc;
    size_t gk = (size_t)(b * Nx + m0 + row) * Dx + h * DHx + kt + kc;
    gload16(qhi + gq, lQh + e);
    gload16(qlo + gq, lQl + e);
    gload16(khi + gk, lKh + e);
    gload16(klo + gk, lKl + e);
    __syncthreads();

    short8 ah[2], al[2], bhf[2], blf[2];
    #pragma unroll
    for (int m = 0; m < 2; m++) {
      int off = (wr * 32 + m * 16 + lr) * 32 + kg;
      ah[m] = *reinterpret_cast<const short8*>(lQh + off);
      al[m] = *reinterpret_cast<const short8*>(lQl + off);
    }
    #pragma unroll
    for (int n = 0; n < 2; n++) {
      int off = (wc * 32 + n * 16 + lr) * 32 + kg;
      bhf[n] = *reinterpret_cast<const short8*>(lKh + off);
      blf[n] = *reinterpret_cast<const short8*>(lKl + off);
    }
    #pragma unroll
    for (int m = 0; m < 2; m++)
      #pragma unroll
      for (int n = 0; n < 2; n++) {
        acc[m][n] = __builtin_amdgcn_mfma_f32_16x16x32_bf16(ah[m], bhf[n], acc[m][n], 0, 0, 0);
        acc[m][n] = __builtin_amdgcn_mfma_f32_16x16x32_bf16(ah[m], blf[n], acc[m][n], 0, 0, 0);
        acc[m][n] = __builtin_amdgcn_mfma_f32_16x16x32_bf16(al[m], bhf[n], acc[m][n], 0, 0, 0);
      }
    __syncthreads();
  }

  const int rbase = (lane >> 4) * 4;
  #pragma unroll
  for (int m = 0; m < 2; m++) {
    #pragma unroll
    for (int n = 0; n < 2; n++) {
      int mg = m0 + wc * 32 + n * 16 + lr;
      #pragma unroll
      for (int r = 0; r < 4; r++) {
        int ng = n0 + wr * 32 + m * 16 + rbase + r;
        unsigned char iv = idx8[(size_t)(b * Nx + ng) * Nx + mg];
        float bias = qrel[((size_t)(b * Nx + ng) * Hx + h) * Kx + iv];
        scores[((size_t)bh * Nx + ng) * Nx + mg] = (acc[m][n][r] + bias) * 0.125f;
      }
    }
  }
}

// ---------------------------------------------------------------------------
// Wave-per-row softmax + 10-bin histogram.  Writes P as bf16 IN-PLACE into the
// scores buffer (first 1024 B of each 2048 B row) + normalized attnK.
// ---------------------------------------------------------------------------
__global__ __launch_bounds__(256) void softmax_wave(float* scores,
                                                    const unsigned char* __restrict__ idx8,
                                                    float* __restrict__ attnK) {
  const int tid = threadIdx.x;
  const int lane = tid & 63;
  const int wid = tid >> 6;
  const int row = blockIdx.x * 4 + wid;          // (b*H+h)*N + n
  const int n = row & (Nx - 1);
  const int b = row >> 12;
  float* s = scores + (size_t)row * Nx;

  float4 v0 = reinterpret_cast<const float4*>(s)[lane * 2];
  float4 v1 = reinterpret_cast<const float4*>(s)[lane * 2 + 1];
  float p[8] = {v0.x, v0.y, v0.z, v0.w, v1.x, v1.y, v1.z, v1.w};

  float mx = p[0];
  #pragma unroll
  for (int j = 1; j < 8; j++) mx = fmaxf(mx, p[j]);
  mx = wave_max(mx);

  float sum = 0.f;
  #pragma unroll
  for (int j = 0; j < 8; j++) { p[j] = expf(p[j] - mx); sum += p[j]; }
  sum = wave_sum(sum);
  float inv = 1.0f / sum;

  const unsigned char* idr = idx8 + (size_t)(b * Nx + n) * Nx + lane * 8;
  uchar4 c0 = *reinterpret_cast<const uchar4*>(idr);
  uchar4 c1 = *reinterpret_cast<const uchar4*>(idr + 4);
  int iv[8] = {c0.x, c0.y, c0.z, c0.w, c1.x, c1.y, c1.z, c1.w};

  float bins[Kx];
  #pragma unroll
  for (int kk = 0; kk < Kx; kk++) bins[kk] = 0.f;
  #pragma unroll
  for (int j = 0; j < 8; j++)
    #pragma unroll
    for (int kk = 0; kk < Kx; kk++) bins[kk] += (iv[j] == kk) ? p[j] : 0.f;
  #pragma unroll
  for (int kk = 0; kk < Kx; kk++) bins[kk] = wave_sum(bins[kk]);

  // write P (bf16, normalized) in place
  short8 sv;
  #pragma unroll
  for (int j = 0; j < 8; j++) sv[j] = (short)f2bf(p[j] * inv);
  u16* prow = reinterpret_cast<u16*>(s);
  *reinterpret_cast<short8*>(prow + lane * 8) = sv;

  if (lane == 0) {
    #pragma unroll
    for (int kk = 0; kk < Kx; kk++) attnK[(size_t)row * Kx + kk] = bins[kk] * inv;
  }
}

// ---------------------------------------------------------------------------
// O = P @ V + attnK @ rel_v  via MFMA (P bf16 x split V^T), split-bf16 out.
// 32-row n-tiles: grid (16, 32) = 512 blocks (2/CU).  m-chunk = 64 (2 k-slices).
// LDS ~24 KB: lP[2 kslice][32][32], V stg [hi/lo][2 kslice][64 dh][32].
// ---------------------------------------------------------------------------
__global__ __launch_bounds__(256) void pv_mfma(
    const u16* __restrict__ P,              // [bh*N + n][stride 1024 u16]
    const u16* __restrict__ vThi, const u16* __restrict__ vTlo,  // [512][2048]
    const float* __restrict__ attnK, const float* __restrict__ rel_v,
    u16* __restrict__ ohi, u16* __restrict__ olo) {
  __shared__ __align__(16) u16 lP[2 * 32 * 32];       // [ks][row][col] 4 KB
  __shared__ __align__(16) u16 sVh[2 * 64 * 32];      // [ks][dh][col] 8 KB
  __shared__ __align__(16) u16 sVl[2 * 64 * 32];      // 8 KB
  __shared__ float aKs[32][Kx];
  __shared__ float RelVs[Kx][DHx];

  const int bh = blockIdx.y;
  const int b = bh >> 3, h = bh & 7;
  const int n0 = blockIdx.x * 32;
  const int tid = threadIdx.x;
  const int lane = tid & 63;
  const int wid = tid >> 6;
  const int wr = wid >> 1, wc = wid & 1;   // wr: 16-row half, wc: 32-dh half
  const int kg = (lane >> 4) * 8;
  const int lr = lane & 15;
  const int rbase = (lane >> 4) * 4;

  for (int t = tid; t < 32 * Kx; t += 256)
    aKs[t / Kx][t % Kx] = attnK[(size_t)(bh * Nx + n0 + t / Kx) * Kx + t % Kx];
  for (int t = tid; t < Kx * DHx; t += 256)
    RelVs[t / DHx][t % DHx] = rel_v[t];

  f32x4 acc[2];
  acc[0] = (f32x4)(0.0f);
  acc[1] = (f32x4)(0.0f);

  for (int mt = 0; mt < Nx; mt += 64) {
    // stage P chunk: 2 k-slices x 32 rows x 32 cols = 2048 elems, 1 round
    {
      int e = tid * 8;
      int ks = e >> 10, row = (e >> 5) & 31, col = e & 31;
      gload16(P + (size_t)(bh * Nx + n0 + row) * 1024 + mt + ks * 32 + col, lP + e);
    }
    // stage V chunk: 2 ks x 64 dh x 32 cols = 4096 elems each for hi/lo, 2 rounds
    #pragma unroll
    for (int rr = 0; rr < 2; rr++) {
      int e = rr * 2048 + tid * 8;
      int ks = e >> 11, dh = (e >> 5) & 63, col = e & 31;
      size_t gv = (size_t)(h * DHx + dh) * 2048 + b * Nx + mt + ks * 32 + col;
      gload16(vThi + gv, sVh + e);
      gload16(vTlo + gv, sVl + e);
    }
    __syncthreads();

    short8 pa[2];
    #pragma unroll
    for (int ks = 0; ks < 2; ks++)
      pa[ks] = *reinterpret_cast<const short8*>(lP + ks * 1024 + (wr * 16 + lr) * 32 + kg);
    #pragma unroll
    for (int f = 0; f < 2; f++) {
      int dh = wc * 32 + f * 16 + lr;
      #pragma unroll
      for (int ks = 0; ks < 2; ks++) {
        short8 vh = *reinterpret_cast<const short8*>(sVh + ks * 2048 + dh * 32 + kg);
        short8 vl = *reinterpret_cast<const short8*>(sVl + ks * 2048 + dh * 32 + kg);
        acc[f] = __builtin_amdgcn_mfma_f32_16x16x32_bf16(pa[ks], vh, acc[f], 0, 0, 0);
        acc[f] = __builtin_amdgcn_mfma_f32_16x16x32_bf16(pa[ks], vl, acc[f], 0, 0, 0);
      }
    }
    __syncthreads();
  }

  #pragma unroll
  for (int f = 0; f < 2; f++) {
    int dl = wc * 32 + f * 16 + lr;
    float rv[Kx];
    #pragma unroll
    for (int kk = 0; kk < Kx; kk++) rv[kk] = RelVs[kk][dl];
    #pragma unroll
    for (int r = 0; r < 4; r++) {
      int nl = wr * 16 + rbase + r;
      float val = acc[f][r];
      #pragma unroll
      for (int kk = 0; kk < Kx; kk++) val += aKs[nl][kk] * rv[kk];
      size_t oo = (size_t)(b * Nx + n0 + nl) * Dx + h * DHx + dl;
      u16 hh = f2bf(val);
      ohi[oo] = hh;
      olo[oo] = f2bf(val - bf2f(hh));
    }
  }
}

// ---------------------------------------------------------------------------
extern "C" void kernel_launch(void* const* d_in, const int* in_sizes, int n_in,
                              void* d_out, int out_size, void* d_ws, size_t ws_size,
                              hipStream_t stream) {
  const float* x_in  = (const float*)d_in[0];
  const float* coord = (const float*)d_in[1];
  const float* ln1_g = (const float*)d_in[2];
  const float* ln1_b = (const float*)d_in[3];
  const float* wq    = (const float*)d_in[4];
  const float* bq    = (const float*)d_in[5];
  const float* wk    = (const float*)d_in[6];
  const float* bk    = (const float*)d_in[7];
  const float* wv    = (const float*)d_in[8];
  const float* bv    = (const float*)d_in[9];
  const float* wo    = (const float*)d_in[10];
  const float* bo    = (const float*)d_in[11];
  const float* rel_k = (const float*)d_in[12];
  const float* rel_v = (const float*)d_in[13];
  const float* ln2_g = (const float*)d_in[14];
  const float* ln2_b = (const float*)d_in[15];
  const float* w1    = (const float*)d_in[16];
  const float* b1    = (const float*)d_in[17];
  const float* w2    = (const float*)d_in[18];
  const float* b2    = (const float*)d_in[19];
  const float* lnf_g = (const float*)d_in[20];
  const float* lnf_b = (const float*)d_in[21];

  float* x = (float*)d_out;
  constexpr size_t BND  = (size_t)Bx * Nx * Dx;       // 1048576
  constexpr size_t SC   = (size_t)Bx * Hx * Nx * Nx;  // 8388608
  constexpr size_t RELS = (size_t)Bx * Nx * Hx * Kx;
  constexpr size_t QKVW = (size_t)1536 * 512;

  char* w = (char*)d_ws;
  size_t off = 0;
  auto nxt = [&](size_t bytes) -> void* {
    void* p = w + off;
    off = (off + bytes + 255) & ~(size_t)255;
    return p;
  };
  unsigned char* idxb = (unsigned char*)nxt((size_t)Bx * Nx * Nx);
  float* scores = (float*)nxt(4ull * SC);             // aliased: P bf16 rows, ffn1 split
  float* qrel   = (float*)nxt(4ull * RELS);
  float* attnK  = (float*)nxt(4ull * RELS);
  u16* qhi = (u16*)nxt(2ull * BND);
  u16* qlo = (u16*)nxt(2ull * BND);
  u16* khi = (u16*)nxt(2ull * BND);
  u16* klo = (u16*)nxt(2ull * BND);
  u16* vThi = (u16*)nxt(2ull * BND);
  u16* vTlo = (u16*)nxt(2ull * BND);
  u16* hhi = (u16*)nxt(2ull * BND);
  u16* hlo = (u16*)nxt(2ull * BND);
  u16* ohi = (u16*)nxt(2ull * BND);
  u16* olo = (u16*)nxt(2ull * BND);
  u16* wqkvThi = (u16*)nxt(2ull * Lx * QKVW);
  u16* wqkvTlo = (u16*)nxt(2ull * Lx * QKVW);
  u16* woThi = (u16*)nxt(2ull * Lx * Dx * Dx);
  u16* woTlo = (u16*)nxt(2ull * Lx * Dx * Dx);
  u16* w1Thi = (u16*)nxt(2ull * Lx * Dx * Mx);
  u16* w1Tlo = (u16*)nxt(2ull * Lx * Dx * Mx);
  u16* w2Thi = (u16*)nxt(2ull * Lx * Mx * Dx);
  u16* w2Tlo = (u16*)nxt(2ull * Lx * Mx * Dx);
  u16* f1hi = (u16*)scores;
  u16* f1lo = f1hi + (size_t)(Bx * Nx) * Mx;
  u16* Pbuf = (u16*)scores;

  hipMemcpyAsync(x, x_in, BND * sizeof(float), hipMemcpyDeviceToDevice, stream);
  idx_kernel<<<(Bx * Nx * Nx) / 256, 256, 0, stream>>>(coord, idxb);

  dim3 gw(Dx / 32, Dx / 32, Lx);
  wsplitT_kernel<<<gw, 256, 0, stream>>>(wq, wqkvThi, wqkvTlo, Dx, Dx, QKVW);
  wsplitT_kernel<<<gw, 256, 0, stream>>>(wk, wqkvThi + (size_t)512 * 512,
                                         wqkvTlo + (size_t)512 * 512, Dx, Dx, QKVW);
  wsplitT_kernel<<<gw, 256, 0, stream>>>(wv, wqkvThi + (size_t)1024 * 512,
                                         wqkvTlo + (size_t)1024 * 512, Dx, Dx, QKVW);
  wsplitT_kernel<<<gw, 256, 0, stream>>>(wo, woThi, woTlo, Dx, Dx, (size_t)Dx * Dx);
  wsplitT_kernel<<<dim3(Mx / 32, Dx / 32, Lx), 256, 0, stream>>>(
      w1, w1Thi, w1Tlo, Dx, Mx, (size_t)Dx * Mx);
  wsplitT_kernel<<<dim3(Dx / 32, Mx / 32, Lx), 256, 0, stream>>>(
      w2, w2Thi, w2Tlo, Mx, Dx, (size_t)Mx * Dx);

  const int Mrows = Bx * Nx;                 // 2048
  dim3 gqkv(1536 / 64, Mrows / 64);          // 768 blocks
  dim3 gw1(Mx / 128, Mrows / 64);            // 512 blocks
  dim3 gwo(Dx / 128, Mrows / 64, 4);         // 512 blocks, KC=128
  dim3 gw2(Dx / 128, Mrows / 64, 4);         // 512 blocks, KC=512
  dim3 gs(Nx / 64, Nx / 64, Bx * Hx);        // (8,8,32)
  dim3 gpv(Nx / 32, Bx * Hx);                // (16,32) = 512 blocks

  for (int l = 0; l < Lx; l++) {
    size_t wD = (size_t)l * Dx * Dx;
    size_t w1o = (size_t)l * Dx * Mx;
    size_t w2o = (size_t)l * Mx * Dx;

    ln_split_kernel<<<Mrows, 256, 0, stream>>>(x, ln1_g + l * Dx, ln1_b + l * Dx, hhi, hlo);
    gemm_qkv<<<gqkv, 256, 0, stream>>>(hhi, hlo,
                                       wqkvThi + (size_t)l * QKVW, wqkvTlo + (size_t)l * QKVW,
                                       bq + l * Dx, bk + l * Dx, bv + l * Dx,
                                       qhi, qlo, khi, klo, vThi, vTlo);
    qrel_kernel<<<(Bx * Nx * Hx * Kx + 255) / 256, 256, 0, stream>>>(
        qhi, qlo, rel_k + (size_t)l * Kx * DHx, qrel);
    scores_mfma<<<gs, 256, 0, stream>>>(qhi, qlo, khi, klo, qrel, idxb, scores);
    softmax_wave<<<Bx * Hx * Nx / 4, 256, 0, stream>>>(scores, idxb, attnK);
    pv_mfma<<<gpv, 256, 0, stream>>>(Pbuf, vThi, vTlo, attnK,
                                     rel_v + (size_t)l * Kx * DHx, ohi, olo);
    gemm_splitk<128><<<gwo, 256, 0, stream>>>(ohi, olo, woThi + wD, woTlo + wD,
                                              bo + l * Dx, x, Mrows, Dx, Dx);
    ln_split_kernel<<<Mrows, 256, 0, stream>>>(x, ln2_g + l * Dx, ln2_b + l * Dx, hhi, hlo);
    gemm_mfma<64, 128, 2><<<gw1, 256, 0, stream>>>(hhi, hlo, w1Thi + w1o, w1Tlo + w1o,
                                                   b1 + l * Mx, nullptr, f1hi, f1lo,
                                                   Mrows, Mx, Dx);
    gemm_splitk<512><<<gw2, 256, 0, stream>>>(f1hi, f1lo, w2Thi + w2o, w2Tlo + w2o,
                                              b2 + l * Dx, x, Mrows, Dx, Mx);
  }
  ln_kernel<<<Mrows, 256, 0, stream>>>(x, lnf_g, lnf_b, x);
}